// Round 6
// baseline (66.908 us; speedup 1.0000x reference)
//
#include <hip/hip_runtime.h>
#include <hip/hip_bf16.h>

#define D_MODEL 1024
#define D_STATE 16
#define BATCH   4
#define SEQ     2048
#define ROWS    (BATCH*SEQ)   // 8192
#define WIN     64            // FIR window; decay<=0.55 => decay^64 < 1e-16

// ---------------------------------------------------------------------------
// Kernel A: blocks 0..1023 -> bx projection (8 rows each);
//           blocks 1024..1039 -> Kbar (one n each).
// ---------------------------------------------------------------------------
#define K1_ROWS 8
__global__ __launch_bounds__(256) void k_proj(const float* __restrict__ x,
                                              const float* __restrict__ Bw,
                                              const float* __restrict__ A_log,
                                              float* __restrict__ bx,
                                              float* __restrict__ KbarT) {
    __shared__ float xs[K1_ROWS][1024];               // 32 KB (aliased by kbar path)
    __shared__ float red[4][8][K1_ROWS][2];           // [wave][np][row][q]
    const int tid = threadIdx.x;

    if (blockIdx.x >= ROWS / K1_ROWS) {
        // ---- Kbar path (16 blocks) ----
        const int n = blockIdx.x - ROWS / K1_ROWS;
        float* l2   = &xs[0][0];                      // 1024 floats
        float* kred = &xs[1][0];                      // 4*64 floats
        const int delta = tid & 63;
        const int c     = tid >> 6;
        for (int d = tid; d < D_MODEL; d += 256) {
            float a = A_log[d * D_STATE + n];
            l2[d] = -expf(a) * 1.4426950408889634f;   // log2(decay)
        }
        __syncthreads();
        const float fdelta = (float)delta;
        float acc = 0.f;
        const int d0 = c * 256;
        for (int d = d0; d < d0 + 256; ++d)
            acc += exp2f(fdelta * l2[d]);
        kred[c * WIN + delta] = acc;
        __syncthreads();
        if (tid < WIN)
            KbarT[tid * D_STATE + n] =
                (kred[tid] + kred[WIN + tid] + kred[2 * WIN + tid] + kred[3 * WIN + tid])
                * (1.0f / 1024.0f);
        return;
    }

    // ---- bx path ----
    const int np   = tid & 7;
    const int dblk = tid >> 3;
    const int row0 = blockIdx.x * K1_ROWS;
    const int lane = tid & 63, wid = tid >> 6;

    float4 bw0[8], bw1[8];
    {
        const float4* p0 = reinterpret_cast<const float4*>(Bw + (size_t)(2 * np    ) * 1024 + dblk * 32);
        const float4* p1 = reinterpret_cast<const float4*>(Bw + (size_t)(2 * np + 1) * 1024 + dblk * 32);
#pragma unroll
        for (int j = 0; j < 8; ++j) { bw0[j] = p0[j]; bw1[j] = p1[j]; }
    }

    const int chunk = tid >> 3;
    const int slotw = ((tid & 7) + chunk) & 7;
#pragma unroll
    for (int r = 0; r < K1_ROWS; ++r) {
        float4 v = reinterpret_cast<const float4*>(x + (size_t)(row0 + r) * 1024)[tid];
        *reinterpret_cast<float4*>(&xs[r][chunk * 32 + slotw * 4]) = v;
    }
    __syncthreads();

    float a0[K1_ROWS], a1[K1_ROWS];
#pragma unroll
    for (int r = 0; r < K1_ROWS; ++r) { a0[r] = 0.f; a1[r] = 0.f; }

#pragma unroll
    for (int r = 0; r < K1_ROWS; ++r) {
#pragma unroll
        for (int j = 0; j < 8; ++j) {
            const int slot = (j + dblk) & 7;
            float4 xv = *reinterpret_cast<const float4*>(&xs[r][dblk * 32 + slot * 4]);
            a0[r] = fmaf(xv.x, bw0[j].x, a0[r]); a0[r] = fmaf(xv.y, bw0[j].y, a0[r]);
            a0[r] = fmaf(xv.z, bw0[j].z, a0[r]); a0[r] = fmaf(xv.w, bw0[j].w, a0[r]);
            a1[r] = fmaf(xv.x, bw1[j].x, a1[r]); a1[r] = fmaf(xv.y, bw1[j].y, a1[r]);
            a1[r] = fmaf(xv.z, bw1[j].z, a1[r]); a1[r] = fmaf(xv.w, bw1[j].w, a1[r]);
        }
    }

#pragma unroll
    for (int r = 0; r < K1_ROWS; ++r) {
        float v0 = a0[r], v1 = a1[r];
        v0 += __shfl_xor(v0, 8);  v1 += __shfl_xor(v1, 8);
        v0 += __shfl_xor(v0, 16); v1 += __shfl_xor(v1, 16);
        v0 += __shfl_xor(v0, 32); v1 += __shfl_xor(v1, 32);
        a0[r] = v0; a1[r] = v1;
    }
    if (lane < 8) {
#pragma unroll
        for (int r = 0; r < K1_ROWS; ++r) {
            red[wid][lane][r][0] = a0[r];
            red[wid][lane][r][1] = a1[r];
        }
    }
    __syncthreads();
    if (tid < K1_ROWS * 16) {
        const int r = tid >> 4, n = tid & 15;
        float v = red[0][n >> 1][r][n & 1] + red[1][n >> 1][r][n & 1]
                + red[2][n >> 1][r][n & 1] + red[3][n >> 1][r][n & 1];
        bx[(size_t)(row0 + r) * D_STATE + n] = v;
    }
}

// ---------------------------------------------------------------------------
// Kernel B (FIR + matvec + LN fused): 256 thr, 4 rows/block, grid 2048.
// ---------------------------------------------------------------------------
#define KB_ROWS 4
__global__ __launch_bounds__(256, 4) void k_fused(const float* __restrict__ x,
                                                  const float* __restrict__ bxg,
                                                  const float* __restrict__ KbarT,
                                                  const float* __restrict__ Cw,
                                                  const float* __restrict__ Dp,
                                                  const float* __restrict__ gamma,
                                                  const float* __restrict__ beta,
                                                  float* __restrict__ out) {
    const int tid = threadIdx.x;
    const int row0 = blockIdx.x * KB_ROWS;
    const int lane = tid & 63, wid = tid >> 6;
    __shared__ float kb[WIN * D_STATE];               // [delta][n], 4 KB
    __shared__ float hm_s[KB_ROWS][D_STATE];
    __shared__ float red_s[KB_ROWS][4], red_q[KB_ROWS][4];

    reinterpret_cast<float4*>(kb)[tid] = reinterpret_cast<const float4*>(KbarT)[tid];

    float4 cw[4][4];
#pragma unroll
    for (int j = 0; j < 4; ++j) {
        const float4* p = reinterpret_cast<const float4*>(Cw + (size_t)(tid * 4 + j) * D_STATE);
#pragma unroll
        for (int q = 0; q < 4; ++q) cw[j][q] = p[q];
    }
    const float4 Dq = reinterpret_cast<const float4*>(Dp)[tid];
    const float4 gq = reinterpret_cast<const float4*>(gamma)[tid];
    const float4 bq = reinterpret_cast<const float4*>(beta)[tid];
    __syncthreads();

    // ---- FIR: tid = p*4+dc ----
    {
        const int p = tid >> 2, dc = tid & 3;
        const int r = p >> 4, n = p & 15;
        const int row = row0 + r;
        const int t = row & (SEQ - 1);
        const float* bp = bxg + (size_t)row * D_STATE + n;
        float acc = 0.f;
        if ((row0 & (SEQ - 1)) >= WIN) {
#pragma unroll
            for (int j = 0; j < 16; ++j) {
                const int delta = dc * 16 + j;
                acc = fmaf(kb[delta * D_STATE + n], bp[-(ptrdiff_t)delta * D_STATE], acc);
            }
        } else {
#pragma unroll
            for (int j = 0; j < 16; ++j) {
                const int delta = dc * 16 + j;
                if (delta <= t)
                    acc = fmaf(kb[delta * D_STATE + n], bp[-(ptrdiff_t)delta * D_STATE], acc);
            }
        }
        acc += __shfl_xor(acc, 1);
        acc += __shfl_xor(acc, 2);
        if (dc == 0) hm_s[r][n] = acc;
    }
    __syncthreads();

    float4 y[KB_ROWS];
#pragma unroll
    for (int r = 0; r < KB_ROWS; ++r) {
        const size_t row = row0 + r;
        const float4* hp = reinterpret_cast<const float4*>(&hm_s[r][0]);
        const float4 h0 = hp[0], h1 = hp[1], h2 = hp[2], h3 = hp[3];
        const float4 xq = reinterpret_cast<const float4*>(x + row * D_MODEL)[tid];

        float4 v;
#pragma unroll
        for (int j = 0; j < 4; ++j) {
            float a = 0.f;
            a = fmaf(h0.x, cw[j][0].x, a); a = fmaf(h0.y, cw[j][0].y, a);
            a = fmaf(h0.z, cw[j][0].z, a); a = fmaf(h0.w, cw[j][0].w, a);
            a = fmaf(h1.x, cw[j][1].x, a); a = fmaf(h1.y, cw[j][1].y, a);
            a = fmaf(h1.z, cw[j][1].z, a); a = fmaf(h1.w, cw[j][1].w, a);
            a = fmaf(h2.x, cw[j][2].x, a); a = fmaf(h2.y, cw[j][2].y, a);
            a = fmaf(h2.z, cw[j][2].z, a); a = fmaf(h2.w, cw[j][2].w, a);
            a = fmaf(h3.x, cw[j][3].x, a); a = fmaf(h3.y, cw[j][3].y, a);
            a = fmaf(h3.z, cw[j][3].z, a); a = fmaf(h3.w, cw[j][3].w, a);
            ((float*)&v)[j] = a;
        }
        v.x = fmaf(Dq.x, xq.x, v.x);
        v.y = fmaf(Dq.y, xq.y, v.y);
        v.z = fmaf(Dq.z, xq.z, v.z);
        v.w = fmaf(Dq.w, xq.w, v.w);
        y[r] = v;

        float s  = v.x + v.y + v.z + v.w;
        float sq = v.x*v.x + v.y*v.y + v.z*v.z + v.w*v.w;
        s += __shfl_xor(s, 1);  sq += __shfl_xor(sq, 1);
        s += __shfl_xor(s, 2);  sq += __shfl_xor(sq, 2);
        s += __shfl_xor(s, 4);  sq += __shfl_xor(sq, 4);
        s += __shfl_xor(s, 8);  sq += __shfl_xor(sq, 8);
        s += __shfl_xor(s, 16); sq += __shfl_xor(sq, 16);
        s += __shfl_xor(s, 32); sq += __shfl_xor(sq, 32);
        if (lane == 0) { red_s[r][wid] = s; red_q[r][wid] = sq; }
    }
    __syncthreads();

#pragma unroll
    for (int r = 0; r < KB_ROWS; ++r) {
        const size_t row = row0 + r;
        const float ssum = red_s[r][0] + red_s[r][1] + red_s[r][2] + red_s[r][3];
        const float ssq  = red_q[r][0] + red_q[r][1] + red_q[r][2] + red_q[r][3];
        const float mu   = ssum * (1.0f / 1024.0f);
        const float var  = ssq * (1.0f / 1024.0f) - mu * mu;
        const float inv  = rsqrtf(var + 1e-5f);
        const float4 v = y[r];
        float4 o;
        o.x = fmaf((v.x - mu) * inv, gq.x, bq.x);
        o.y = fmaf((v.y - mu) * inv, gq.y, bq.y);
        o.z = fmaf((v.z - mu) * inv, gq.z, bq.z);
        o.w = fmaf((v.w - mu) * inv, gq.w, bq.w);
        reinterpret_cast<float4*>(out + row * D_MODEL)[tid] = o;
    }
}

extern "C" void kernel_launch(void* const* d_in, const int* in_sizes, int n_in,
                              void* d_out, int out_size, void* d_ws, size_t ws_size,
                              hipStream_t stream) {
    (void)in_sizes; (void)n_in; (void)out_size; (void)ws_size;
    const float* x     = (const float*)d_in[0];
    const float* A_log = (const float*)d_in[1];
    const float* B_w   = (const float*)d_in[2];
    const float* C_w   = (const float*)d_in[3];
    const float* Dp    = (const float*)d_in[4];
    const float* gamma = (const float*)d_in[5];
    const float* beta  = (const float*)d_in[6];
    float* out = (float*)d_out;

    float* bx = (float*)d_ws;                       // ROWS*16 floats (512 KB)
    float* kb = bx + (size_t)ROWS * D_STATE;        // WIN*16 floats (4 KB)

    k_proj <<<ROWS / K1_ROWS + D_STATE, 256, 0, stream>>>(x, B_w, A_log, bx, kb);
    k_fused<<<ROWS / KB_ROWS,           256, 0, stream>>>(x, bx, kb, C_w, Dp, gamma, beta, out);
}

// Round 7
// 59.532 us; speedup vs baseline: 1.1239x; 1.1239x over previous
//
#include <hip/hip_runtime.h>
#include <hip/hip_bf16.h>

#define D_MODEL 1024
#define D_STATE 16
#define BATCH   4
#define SEQ     2048
#define ROWS    (BATCH*SEQ)   // 8192
#define WIN     64            // FIR window; decay<=0.55 => decay^64 < 1e-16

// ---------------------------------------------------------------------------
// K1: blocks 0..1023 -> bx projection (8 rows each); blocks 1024..1039 -> Kbar.
// ---------------------------------------------------------------------------
#define K1_ROWS 8
__global__ __launch_bounds__(256, 4) void k_proj(const float* __restrict__ x,
                                                 const float* __restrict__ Bw,
                                                 const float* __restrict__ A_log,
                                                 float* __restrict__ bx,
                                                 float* __restrict__ KbarT) {
    __shared__ float xs[K1_ROWS][1024];               // 32 KB (aliased by kbar path)
    __shared__ float red[4][8][K1_ROWS][2];           // [wave][np][row][q]
    const int tid = threadIdx.x;

    if (blockIdx.x >= ROWS / K1_ROWS) {
        // ---- Kbar path (16 blocks) ----
        const int n = blockIdx.x - ROWS / K1_ROWS;
        float* l2   = &xs[0][0];                      // 1024 floats
        float* kred = &xs[1][0];                      // 4*64 floats
        const int delta = tid & 63;
        const int c     = tid >> 6;
        for (int d = tid; d < D_MODEL; d += 256) {
            float a = A_log[d * D_STATE + n];
            l2[d] = -expf(a) * 1.4426950408889634f;   // log2(decay)
        }
        __syncthreads();
        const float fdelta = (float)delta;
        float acc = 0.f;
        const int d0 = c * 256;
        for (int d = d0; d < d0 + 256; ++d)
            acc += exp2f(fdelta * l2[d]);
        kred[c * WIN + delta] = acc;
        __syncthreads();
        if (tid < WIN)
            KbarT[tid * D_STATE + n] =
                (kred[tid] + kred[WIN + tid] + kred[2 * WIN + tid] + kred[3 * WIN + tid])
                * (1.0f / 1024.0f);
        return;
    }

    // ---- bx path ----
    const int np   = tid & 7;
    const int dblk = tid >> 3;
    const int row0 = blockIdx.x * K1_ROWS;
    const int lane = tid & 63, wid = tid >> 6;

    float4 bw0[8], bw1[8];
    {
        const float4* p0 = reinterpret_cast<const float4*>(Bw + (size_t)(2 * np    ) * 1024 + dblk * 32);
        const float4* p1 = reinterpret_cast<const float4*>(Bw + (size_t)(2 * np + 1) * 1024 + dblk * 32);
#pragma unroll
        for (int j = 0; j < 8; ++j) { bw0[j] = p0[j]; bw1[j] = p1[j]; }
    }

    const int chunk = tid >> 3;
    const int slotw = ((tid & 7) + chunk) & 7;
#pragma unroll
    for (int r = 0; r < K1_ROWS; ++r) {
        float4 v = reinterpret_cast<const float4*>(x + (size_t)(row0 + r) * 1024)[tid];
        *reinterpret_cast<float4*>(&xs[r][chunk * 32 + slotw * 4]) = v;
    }
    __syncthreads();

    float a0[K1_ROWS], a1[K1_ROWS];
#pragma unroll
    for (int r = 0; r < K1_ROWS; ++r) { a0[r] = 0.f; a1[r] = 0.f; }

#pragma unroll
    for (int r = 0; r < K1_ROWS; ++r) {
#pragma unroll
        for (int j = 0; j < 8; ++j) {
            const int slot = (j + dblk) & 7;
            float4 xv = *reinterpret_cast<const float4*>(&xs[r][dblk * 32 + slot * 4]);
            a0[r] = fmaf(xv.x, bw0[j].x, a0[r]); a0[r] = fmaf(xv.y, bw0[j].y, a0[r]);
            a0[r] = fmaf(xv.z, bw0[j].z, a0[r]); a0[r] = fmaf(xv.w, bw0[j].w, a0[r]);
            a1[r] = fmaf(xv.x, bw1[j].x, a1[r]); a1[r] = fmaf(xv.y, bw1[j].y, a1[r]);
            a1[r] = fmaf(xv.z, bw1[j].z, a1[r]); a1[r] = fmaf(xv.w, bw1[j].w, a1[r]);
        }
    }

#pragma unroll
    for (int r = 0; r < K1_ROWS; ++r) {
        float v0 = a0[r], v1 = a1[r];
        v0 += __shfl_xor(v0, 8);  v1 += __shfl_xor(v1, 8);
        v0 += __shfl_xor(v0, 16); v1 += __shfl_xor(v1, 16);
        v0 += __shfl_xor(v0, 32); v1 += __shfl_xor(v1, 32);
        a0[r] = v0; a1[r] = v1;
    }
    if (lane < 8) {
#pragma unroll
        for (int r = 0; r < K1_ROWS; ++r) {
            red[wid][lane][r][0] = a0[r];
            red[wid][lane][r][1] = a1[r];
        }
    }
    __syncthreads();
    if (tid < K1_ROWS * 16) {
        const int r = tid >> 4, n = tid & 15;
        float v = red[0][n >> 1][r][n & 1] + red[1][n >> 1][r][n & 1]
                + red[2][n >> 1][r][n & 1] + red[3][n >> 1][r][n & 1];
        bx[(size_t)(row0 + r) * D_STATE + n] = v;
    }
}

// ---------------------------------------------------------------------------
// K2: FIR, float4 over n. 256 thr = 64 rows x 4 n-quads, grid 128. (R5-proven)
// ---------------------------------------------------------------------------
__global__ __launch_bounds__(256) void k_fir(const float* __restrict__ bx,
                                             const float* __restrict__ KbarT,
                                             float* __restrict__ hm) {
    __shared__ float4 kb4[WIN][4];
    const int tid = threadIdx.x;
    kb4[tid >> 2][tid & 3] = reinterpret_cast<const float4*>(KbarT)[tid];
    __syncthreads();

    const int nq  = tid & 3;
    const int row = blockIdx.x * 64 + (tid >> 2);
    const int t   = row & (SEQ - 1);
    const float4* bp = reinterpret_cast<const float4*>(bx + (size_t)row * D_STATE) + nq;
    float4 acc = {0.f, 0.f, 0.f, 0.f};
    if (t >= WIN - 1) {
#pragma unroll
        for (int dl = 0; dl < WIN; ++dl) {
            float4 b = bp[-(ptrdiff_t)dl * 4];
            float4 k = kb4[dl][nq];
            acc.x = fmaf(k.x, b.x, acc.x); acc.y = fmaf(k.y, b.y, acc.y);
            acc.z = fmaf(k.z, b.z, acc.z); acc.w = fmaf(k.w, b.w, acc.w);
        }
    } else {
        for (int dl = 0; dl <= t; ++dl) {
            float4 b = bp[-(ptrdiff_t)dl * 4];
            float4 k = kb4[dl][nq];
            acc.x = fmaf(k.x, b.x, acc.x); acc.y = fmaf(k.y, b.y, acc.y);
            acc.z = fmaf(k.z, b.z, acc.z); acc.w = fmaf(k.w, b.w, acc.w);
        }
    }
    reinterpret_cast<float4*>(hm + (size_t)row * D_STATE)[nq] = acc;
}

// ---------------------------------------------------------------------------
// K3: y = hm @ C_w^T + D*x ; out = LN(y)*gamma + beta. Fully float4.
// 8 rows/block (grid 1024) to amortize C_w reg-staging; two half-groups of 4
// rows; 2 barriers total; no kb/LDS staging beyond the reduction scratch.
// ---------------------------------------------------------------------------
#define KO_ROWS 8
__global__ __launch_bounds__(256, 4) void k_out(const float* __restrict__ x,
                                                const float* __restrict__ hm,
                                                const float* __restrict__ Cw,
                                                const float* __restrict__ Dp,
                                                const float* __restrict__ gamma,
                                                const float* __restrict__ beta,
                                                float* __restrict__ out) {
    const int tid = threadIdx.x;
    const int row0 = blockIdx.x * KO_ROWS;
    const int lane = tid & 63, wid = tid >> 6;
    __shared__ float red_s[2][4][4], red_q[2][4][4];   // [half][row][wave]

    // cw[j][q] = C_w[4*tid+j][4q .. 4q+3]  -> 64 VGPRs, loaded once per 8 rows
    float4 cw[4][4];
#pragma unroll
    for (int j = 0; j < 4; ++j) {
        const float4* p = reinterpret_cast<const float4*>(Cw + (size_t)(tid * 4 + j) * D_STATE);
#pragma unroll
        for (int q = 0; q < 4; ++q) cw[j][q] = p[q];
    }
    const float4 Dq = reinterpret_cast<const float4*>(Dp)[tid];
    const float4 gq = reinterpret_cast<const float4*>(gamma)[tid];
    const float4 bq = reinterpret_cast<const float4*>(beta)[tid];

    for (int h = 0; h < 2; ++h) {
        float4 y[4];
#pragma unroll
        for (int rr = 0; rr < 4; ++rr) {
            const size_t row = row0 + h * 4 + rr;
            const float4* hp = reinterpret_cast<const float4*>(hm + row * D_STATE);
            const float4 h0 = hp[0], h1 = hp[1], h2 = hp[2], h3 = hp[3];  // uniform
            const float4 xq = reinterpret_cast<const float4*>(x + row * D_MODEL)[tid];

            float4 v;
#pragma unroll
            for (int j = 0; j < 4; ++j) {
                float a = 0.f;
                a = fmaf(h0.x, cw[j][0].x, a); a = fmaf(h0.y, cw[j][0].y, a);
                a = fmaf(h0.z, cw[j][0].z, a); a = fmaf(h0.w, cw[j][0].w, a);
                a = fmaf(h1.x, cw[j][1].x, a); a = fmaf(h1.y, cw[j][1].y, a);
                a = fmaf(h1.z, cw[j][1].z, a); a = fmaf(h1.w, cw[j][1].w, a);
                a = fmaf(h2.x, cw[j][2].x, a); a = fmaf(h2.y, cw[j][2].y, a);
                a = fmaf(h2.z, cw[j][2].z, a); a = fmaf(h2.w, cw[j][2].w, a);
                a = fmaf(h3.x, cw[j][3].x, a); a = fmaf(h3.y, cw[j][3].y, a);
                a = fmaf(h3.z, cw[j][3].z, a); a = fmaf(h3.w, cw[j][3].w, a);
                ((float*)&v)[j] = a;
            }
            v.x = fmaf(Dq.x, xq.x, v.x);
            v.y = fmaf(Dq.y, xq.y, v.y);
            v.z = fmaf(Dq.z, xq.z, v.z);
            v.w = fmaf(Dq.w, xq.w, v.w);
            y[rr] = v;

            float s  = v.x + v.y + v.z + v.w;
            float sq = v.x*v.x + v.y*v.y + v.z*v.z + v.w*v.w;
            s += __shfl_xor(s, 1);  sq += __shfl_xor(sq, 1);
            s += __shfl_xor(s, 2);  sq += __shfl_xor(sq, 2);
            s += __shfl_xor(s, 4);  sq += __shfl_xor(sq, 4);
            s += __shfl_xor(s, 8);  sq += __shfl_xor(sq, 8);
            s += __shfl_xor(s, 16); sq += __shfl_xor(sq, 16);
            s += __shfl_xor(s, 32); sq += __shfl_xor(sq, 32);
            if (lane == 0) { red_s[h][rr][wid] = s; red_q[h][rr][wid] = sq; }
        }
        __syncthreads();   // half-h partials visible (distinct buffers per half)

#pragma unroll
        for (int rr = 0; rr < 4; ++rr) {
            const size_t row = row0 + h * 4 + rr;
            const float ssum = red_s[h][rr][0] + red_s[h][rr][1] + red_s[h][rr][2] + red_s[h][rr][3];
            const float ssq  = red_q[h][rr][0] + red_q[h][rr][1] + red_q[h][rr][2] + red_q[h][rr][3];
            const float mu   = ssum * (1.0f / 1024.0f);
            const float var  = ssq * (1.0f / 1024.0f) - mu * mu;
            const float inv  = rsqrtf(var + 1e-5f);
            const float4 v = y[rr];
            float4 o;
            o.x = fmaf((v.x - mu) * inv, gq.x, bq.x);
            o.y = fmaf((v.y - mu) * inv, gq.y, bq.y);
            o.z = fmaf((v.z - mu) * inv, gq.z, bq.z);
            o.w = fmaf((v.w - mu) * inv, gq.w, bq.w);
            reinterpret_cast<float4*>(out + row * D_MODEL)[tid] = o;
        }
    }
}

extern "C" void kernel_launch(void* const* d_in, const int* in_sizes, int n_in,
                              void* d_out, int out_size, void* d_ws, size_t ws_size,
                              hipStream_t stream) {
    (void)in_sizes; (void)n_in; (void)out_size; (void)ws_size;
    const float* x     = (const float*)d_in[0];
    const float* A_log = (const float*)d_in[1];
    const float* B_w   = (const float*)d_in[2];
    const float* C_w   = (const float*)d_in[3];
    const float* Dp    = (const float*)d_in[4];
    const float* gamma = (const float*)d_in[5];
    const float* beta  = (const float*)d_in[6];
    float* out = (float*)d_out;

    float* bx = (float*)d_ws;                       // ROWS*16 floats (512 KB)
    float* kb = bx + (size_t)ROWS * D_STATE;        // WIN*16 floats (4 KB)
    float* hm = kb + WIN * D_STATE;                 // ROWS*16 floats (512 KB)

    k_proj<<<ROWS / K1_ROWS + D_STATE, 256, 0, stream>>>(x, B_w, A_log, bx, kb);
    k_fir <<<ROWS / 64,               256, 0, stream>>>(bx, kb, hm);
    k_out <<<ROWS / KO_ROWS,          256, 0, stream>>>(x, hm, C_w, Dp, gamma, beta, out);
}